// Round 15
// baseline (214.748 us; speedup 1.0000x reference)
//
#include <hip/hip_runtime.h>
#include <cstdint>
#include <cstddef>

#define BATCH 2048
#define NZ 128
#define NGEN 8
#define GRPS 32                 // samples per fc2 group
#define NCT 13                  // fc2 col tiles of 128 (12 full + tail 32)
#define H2_ELEMS 1792           // 32*7*8 (x padded 7->8) per sample, bf16
// ws layout: wsi ints [0 .. 16+8*2048) = 65.6 KB
#define WS_H1_OFF 81920                                  // h1[sample][col] fp32, 2 MB
#define WS_H2_OFF (WS_H1_OFF + BATCH * 256 * 4)          // 2179072
#define WS_W2T_OFF (WS_H2_OFF + BATCH * H2_ELEMS * 2)    // 9519104
#define W2T_GSTRIDE (1568 * 256)                         // fp16 elems per gen
#define NB_W2T (NGEN * 49)                               // 392
#define NB_SLICE (NGEN * 256)                            // 2048 bin+fc1 slice blocks

typedef unsigned int u32;
typedef unsigned short u16;
typedef _Float16 f16x8 __attribute__((ext_vector_type(8)));
typedef _Float16 f16x4 __attribute__((ext_vector_type(4)));
typedef float f32x4 __attribute__((ext_vector_type(4)));

__device__ __forceinline__ float lrelu(float x) { return fmaxf(x, 0.2f * x); }
__device__ __forceinline__ float bflo(u32 u) { union { u32 i; float f; } v; v.i = u << 16; return v.f; }
__device__ __forceinline__ float bfhi(u32 u) { union { u32 i; float f; } v; v.i = u & 0xffff0000u; return v.f; }
__device__ __forceinline__ float bf1(u16 u) { union { u32 i; float f; } v; v.i = ((u32)u) << 16; return v.f; }
__device__ __forceinline__ u16 f2bf(float f) {
    union { float f; u32 i; } v; v.f = f;
    u32 r = v.i + 0x7fffu + ((v.i >> 16) & 1u);   // round-to-nearest-even
    return (u16)(r >> 16);
}
__device__ __forceinline__ float fast_tanh(float x) {
    x = fminf(fmaxf(x, -9.f), 9.f);
    const float e = __expf(2.f * x);
    return (e - 1.f) / (e + 1.f);
}

// ---------------------------------------------------------------------------
// Kernel 1: prep (R14-proven) — three roles, no upstream dependency:
//   [0,392):   W2 transpose fp32[k][n] -> fp16[n][k]
//   [392,2440): bin+fc1 slice (g = idx>>8, s = idx&255): redundant in-block
//     bin via shuffle prefix; slice 0 publishes g's list; all slices do FC1.
// ---------------------------------------------------------------------------
__global__ __launch_bounds__(256) void prep_kernel(
    const float* __restrict__ z, const int* __restrict__ g_idx,
    const float* __restrict__ W1, const float* __restrict__ b1,
    const float* __restrict__ W2, int* __restrict__ wsi,
    float* __restrict__ h1g, _Float16* __restrict__ W2T)
{
    __shared__ _Float16 t[32][264];   // w2t role, 16.5 KB
    __shared__ u16 slist[BATCH];      // bin role, 4 KB
    __shared__ int wtot[4];
    __shared__ float zst[NZ][12];     // fc1 role, 6 KB
    __shared__ int sbv[8];

    const int tid = threadIdx.x;
    const int bx = blockIdx.x;

    if (bx < NB_W2T) {
        const int g = bx / 49;
        const int n0 = (bx % 49) * 32;
        const float* src = W2 + (size_t)g * 256 * 1568;
        const int nl = tid & 31, kh = tid >> 5;
        #pragma unroll 8
        for (int p = 0; p < 32; ++p) {
            const int k = p * 8 + kh;
            t[nl][k] = (_Float16)src[(size_t)k * 1568 + n0 + nl];
        }
        __syncthreads();
        _Float16* dst = W2T + (size_t)g * W2T_GSTRIDE + (size_t)n0 * 256;
        const int n = tid >> 3, k0 = (tid & 7) * 32;
        #pragma unroll
        for (int j = 0; j < 4; ++j)
            *(uint4*)(dst + (size_t)n * 256 + k0 + 8 * j) = *(const uint4*)&t[n][k0 + 8 * j];
        return;
    }

    const int idx = bx - NB_W2T;
    const int g = idx >> 8;
    const int s = idx & 255;

    int match[8];
    int lc = 0;
    {
        const int4 ga = ((const int4*)g_idx)[2 * tid];
        const int4 gb = ((const int4*)g_idx)[2 * tid + 1];
        const int gv[8] = {ga.x, ga.y, ga.z, ga.w, gb.x, gb.y, gb.z, gb.w};
        #pragma unroll
        for (int j = 0; j < 8; ++j)
            if (gv[j] == g) match[lc++] = 8 * tid + j;
    }
    const int lane = tid & 63, wv = tid >> 6;
    int px = lc;
    #pragma unroll
    for (int d = 1; d < 64; d <<= 1) {
        const int y = __shfl_up(px, d);
        if (lane >= d) px += y;
    }
    if (lane == 63) wtot[wv] = px;
    __syncthreads();
    int woff = 0, cnt = 0;
    #pragma unroll
    for (int w = 0; w < 4; ++w) {
        if (w < wv) woff += wtot[w];
        cnt += wtot[w];
    }
    const int myoff = woff + px - lc;
    for (int j = 0; j < lc; ++j) slist[myoff + j] = (u16)match[j];
    __syncthreads();

    if (s == 0) {
        if (tid == 0) wsi[8 + g] = cnt;
        const int padded = ((cnt + GRPS - 1) / GRPS) * GRPS;
        for (int i = tid; i < padded; i += 256)
            wsi[16 + g * 2048 + i] = (i < cnt) ? (int)slist[i] : -1;
    }
    if (s * 8 >= cnt) return;

    if (tid < 8) sbv[tid] = (s * 8 + tid < cnt) ? (int)slist[s * 8 + tid] : -1;
    __syncthreads();
    {
        const int ss = tid >> 5, f = tid & 31;
        float4 v = make_float4(0.f, 0.f, 0.f, 0.f);
        if (sbv[ss] >= 0) v = *(const float4*)(z + (size_t)sbv[ss] * NZ + 4 * f);
        zst[4 * f + 0][ss] = v.x; zst[4 * f + 1][ss] = v.y;
        zst[4 * f + 2][ss] = v.z; zst[4 * f + 3][ss] = v.w;
    }
    __syncthreads();

    const float* W1g = W1 + g * (NZ * 256);
    const int c = tid;
    float acc[8];
    #pragma unroll
    for (int ss = 0; ss < 8; ++ss) acc[ss] = 0.f;
    const float* wp = W1g + c;
    #pragma unroll 4
    for (int k = 0; k < NZ; ++k) {
        const float w = wp[k * 256];
        float av[8];
        *(float4*)&av[0] = *(const float4*)&zst[k][0];
        *(float4*)&av[4] = *(const float4*)&zst[k][4];
        #pragma unroll
        for (int ss = 0; ss < 8; ++ss) acc[ss] += av[ss] * w;
    }
    const float bv = b1[g * 256 + c];
    #pragma unroll
    for (int ss = 0; ss < 8; ++ss) {
        const int bb = sbv[ss];
        if (bb >= 0) h1g[(size_t)bb * 256 + c] = lrelu(acc[ss] + bv);
    }
}

// ---------------------------------------------------------------------------
// Kernel 2: FC2 via fp16 MFMA 16x16x32 (R13/R14-proven).
// ---------------------------------------------------------------------------
__global__ __launch_bounds__(256) void fc2_kernel(
    const _Float16* __restrict__ W2T, const float* __restrict__ b2,
    const int* __restrict__ wsi, const float* __restrict__ h1g,
    u16* __restrict__ h2g)
{
    __shared__ _Float16 afrag[2 * 2 * 8 * 64 * 8];   // 32 KB
    __shared__ int sb[GRPS];

    const int tid = threadIdx.x;
    const int grp = blockIdx.x / NCT;
    const int tile = blockIdx.x % NCT;
    const int gg = grp >> 6;
    const int j = grp & 63;
    const int cnt = wsi[8 + gg];
    if (j * GRPS >= cnt) return;

    if (tid < GRPS) sb[tid] = wsi[16 + gg * 2048 + j * GRPS + tid];
    __syncthreads();
    const _Float16* W2Tg = W2T + (size_t)gg * W2T_GSTRIDE;
    const float* b2g = b2 + gg * 1568;

    {
        const float4* h1p4 = (const float4*)h1g;
        #pragma unroll
        for (int i = 0; i < 8; ++i) {
            const int u = tid + 256 * i;
            const int j4 = u & 1;
            const int lane = (u >> 1) & 63;
            const int kq = (u >> 7) & 7;
            const int mt = (u >> 10) & 1;
            const int s = mt * 16 + (lane & 15);
            const int bb = sb[s];
            float4 v = make_float4(0.f, 0.f, 0.f, 0.f);
            if (bb >= 0) v = h1p4[(size_t)bb * 64 + kq * 8 + ((lane >> 4) << 1) + j4];
            const float vv[4] = {v.x, v.y, v.z, v.w};
            f16x4 hi, lo;
            #pragma unroll
            for (int e = 0; e < 4; ++e) {
                hi[e] = (_Float16)vv[e];
                lo[e] = (_Float16)(vv[e] - (float)hi[e]);
            }
            *(f16x4*)&afrag[(((mt * 2 + 0) * 8 + kq) * 64 + lane) * 8 + 4 * j4] = hi;
            *(f16x4*)&afrag[(((mt * 2 + 1) * 8 + kq) * 64 + lane) * 8 + 4 * j4] = lo;
        }
    }
    __syncthreads();

    const int wave = tid >> 6;
    const int lane = tid & 63;
    const int q = lane >> 4;
    const int nl = lane & 15;
    const int nb0 = tile * 128 + 2 * wave * 16;
    if (nb0 >= 1568) return;

    #pragma unroll
    for (int nt = 0; nt < 2; ++nt) {
        const int nb = nb0 + nt * 16;
        if (nb >= 1568) break;
        const int n = nb + nl;
        const _Float16* bp = W2Tg + (size_t)n * 256 + q * 8;
        f32x4 accA = {0.f, 0.f, 0.f, 0.f}, accB = accA;
        #pragma unroll
        for (int kq = 0; kq < 8; ++kq) {
            const f16x8 b = *(const f16x8*)(bp + kq * 32);
            const f16x8 a0h = *(const f16x8*)&afrag[((0 * 8 + kq) * 64 + lane) * 8];
            const f16x8 a0l = *(const f16x8*)&afrag[((1 * 8 + kq) * 64 + lane) * 8];
            const f16x8 a1h = *(const f16x8*)&afrag[((2 * 8 + kq) * 64 + lane) * 8];
            const f16x8 a1l = *(const f16x8*)&afrag[((3 * 8 + kq) * 64 + lane) * 8];
            accA = __builtin_amdgcn_mfma_f32_16x16x32_f16(a0h, b, accA, 0, 0, 0);
            accA = __builtin_amdgcn_mfma_f32_16x16x32_f16(a0l, b, accA, 0, 0, 0);
            accB = __builtin_amdgcn_mfma_f32_16x16x32_f16(a1h, b, accB, 0, 0, 0);
            accB = __builtin_amdgcn_mfma_f32_16x16x32_f16(a1l, b, accB, 0, 0, 0);
        }
        const float bias = b2g[n];
        const int ci = n / 49, rm = n % 49;
        const int off = ci * 56 + (rm / 7) * 8 + (rm % 7);
        #pragma unroll
        for (int mt = 0; mt < 2; ++mt) {
            const f32x4 a = (mt == 0) ? accA : accB;
            #pragma unroll
            for (int reg = 0; reg < 4; ++reg) {
                const int ss = mt * 16 + q * 4 + reg;
                const int bb = sb[ss];
                if (bb >= 0)
                    h2g[(size_t)bb * H2_ELEMS + off] = f2bf(lrelu(a[reg] + bias));
            }
        }
    }
}

// ---------------------------------------------------------------------------
// conv2 half-pass: output x in [14*H, 14*H+14) for one (co,y) row.
// c1s is bf16, row stride 24 u16: H=0 needs one uint4 (values 0..7),
// H=1 two (values 4..15) — 3 b128/(a,ci) vs 5 with fp32 (40% LDS cut).
// rr[10..11] may hold pad garbage; compile-time guards never touch it.
// ---------------------------------------------------------------------------
template <int H>
__device__ __forceinline__ void conv2_half(
    const u16 (*c1s)[14][24], u16 (*c2s)[28][30],
    const float* cw2g, const float bv, const int co, const int y)
{
    float acc[14];
    #pragma unroll
    for (int xx = 0; xx < 14; ++xx) acc[xx] = bv;
    const int a0 = (y + 1) & 1;
    for (int aa = 0; aa < 2; ++aa) {
        const int a = a0 + 2 * aa;
        const int iy = (y + 1 - a) >> 1;
        if ((unsigned)iy < 14u) {
            #pragma unroll 2
            for (int ci = 0; ci < 16; ++ci) {
                float rr[12];
                if (H == 0) {
                    // rr[j] = c1 value at ix = j, j in 0..7
                    const uint4 qa = *(const uint4*)&c1s[ci][iy][0];
                    rr[0] = bflo(qa.x); rr[1] = bfhi(qa.x);
                    rr[2] = bflo(qa.y); rr[3] = bfhi(qa.y);
                    rr[4] = bflo(qa.z); rr[5] = bfhi(qa.z);
                    rr[6] = bflo(qa.w); rr[7] = bfhi(qa.w);
                } else {
                    // rr[j] = c1 value at ix = 4 + j, j in 0..11
                    const uint4 qa = *(const uint4*)&c1s[ci][iy][0];
                    const uint4 qb = *(const uint4*)&c1s[ci][iy][8];
                    rr[0] = bflo(qa.z); rr[1] = bfhi(qa.z);
                    rr[2] = bflo(qa.w); rr[3] = bfhi(qa.w);
                    rr[4] = bflo(qb.x); rr[5] = bfhi(qb.x);
                    rr[6] = bflo(qb.y); rr[7] = bfhi(qb.y);
                    rr[8] = bflo(qb.z); rr[9] = bfhi(qb.z);
                    rr[10] = bflo(qb.w); rr[11] = bfhi(qb.w);
                }
                const float4 w4 = *(const float4*)(cw2g + ci * 128 + co * 16 + a * 4);
                const float wv[4] = {w4.x, w4.y, w4.z, w4.w};
                #pragma unroll
                for (int xx = 0; xx < 14; ++xx) {
                    const int x = 14 * H + xx;
                    const int c0v = (x + 1) & 1;
                    const int ix0 = (x + 1 - c0v) >> 1;
                    const int li = ix0 - 4 * H;            // compile-time
                    if (ix0 < 14) acc[xx] += rr[li] * wv[c0v];
                    if (ix0 >= 1) acc[xx] += rr[li - 1] * wv[c0v + 2];
                }
            }
        }
    }
    u32* dst = (u32*)&c2s[co][y][0];
    #pragma unroll
    for (int xx = 0; xx < 7; ++xx) {
        const u32 lo = f2bf(lrelu(acc[2 * xx]));
        const u32 hi = f2bf(lrelu(acc[2 * xx + 1]));
        dst[7 * H + xx] = lo | (hi << 16);
    }
}

// ---------------------------------------------------------------------------
// Kernel 3: all three transposed convs, ONE sample per block.
// LDS plan (24.5 KB total, 6 blocks/CU):
//   h2s fp32 [32][7][12] (stride 12: Δiy*12 mod 32 != 0 -> conv1 conflict-free)
//   c1s bf16 [16][14][24] (stride 12 dwords: worst 2-way at Δiy=8 — free)
//   c2s bf16 [8][28][30] aliased over dead h2s (both <= 13.44 KB region)
// ---------------------------------------------------------------------------
__global__ __launch_bounds__(256, 6) void conv_kernel(
    const int* __restrict__ g_idx,
    const float* __restrict__ cw1, const float* __restrict__ cb1,
    const float* __restrict__ cw2, const float* __restrict__ cb2,
    const float* __restrict__ cw3, const float* __restrict__ cb3,
    const u16* __restrict__ h2g, float* __restrict__ out)
{
    __shared__ __align__(16) char smem[13440 + 10752];
    float (*h2s)[7][12] = (float (*)[7][12])smem;            // [32][7][12], 10.5 KB
    u16  (*c2s)[28][30] = (u16 (*)[28][30])smem;             // [8][28][30], 13.4 KB (alias)
    u16  (*c1s)[14][24] = (u16 (*)[14][24])(smem + 13440);   // [16][14][24], 10.5 KB
    __shared__ float w3s[72];

    const int tid = threadIdx.x;
    const int b = blockIdx.x;
    const int g = g_idx[b];
    const float* cw1g = cw1 + g * 8192;
    const float* cb1g = cb1 + g * 16;
    const float* cw2g = cw2 + g * 2048;
    const float* cb2g = cb2 + g * 8;
    const float* cw3g = cw3 + g * 72;
    const float  cb3v = cb3[g];

    // stage h2: thread t = (ci,iy) row; uint4 index t matches h2g layout
    if (tid < 224) {
        const int ci = tid / 7, iy = tid % 7;
        const uint4 qv = ((const uint4*)(h2g + (size_t)b * H2_ELEMS))[tid];
        float* hp = &h2s[ci][iy][0];
        ((float4*)hp)[0] = make_float4(bflo(qv.x), bfhi(qv.x), bflo(qv.y), bfhi(qv.y));
        ((float4*)hp)[1] = make_float4(bflo(qv.z), bfhi(qv.z), bflo(qv.w), bfhi(qv.w));
    }
    if (tid < 72) w3s[tid] = cw3g[tid];
    __syncthreads();

    // conv1: [32,7,7] -> [16,14,14], k=4, s=2; epilogue packs bf16 into c1s
    if (tid < 224) {
        const int co = tid / 14, y = tid % 14;
        float acc[14];
        const float bv = cb1g[co];
        #pragma unroll
        for (int x = 0; x < 14; ++x) acc[x] = bv;
        const int a0 = (y + 1) & 1;
        for (int aa = 0; aa < 2; ++aa) {
            const int a = a0 + 2 * aa;
            const int iy = (y + 1 - a) >> 1;
            if ((unsigned)iy < 7u) {
                #pragma unroll 2
                for (int ci = 0; ci < 32; ++ci) {
                    float rr[8];
                    *(float4*)&rr[0] = *(const float4*)&h2s[ci][iy][0];
                    *(float4*)&rr[4] = *(const float4*)&h2s[ci][iy][4];
                    const float4 w4 = *(const float4*)(cw1g + ci * 256 + co * 16 + a * 4);
                    const float wv[4] = {w4.x, w4.y, w4.z, w4.w};
                    #pragma unroll
                    for (int x = 0; x < 14; ++x) {
                        const int c0v = (x + 1) & 1;
                        const int ix0 = (x + 1 - c0v) >> 1;
                        if (ix0 < 7)  acc[x] += rr[ix0] * wv[c0v];
                        if (ix0 >= 1) acc[x] += rr[ix0 - 1] * wv[c0v + 2];
                    }
                }
            }
        }
        u32* dst = (u32*)&c1s[co][y][0];
        #pragma unroll
        for (int xx = 0; xx < 7; ++xx) {
            const u32 lo = f2bf(lrelu(acc[2 * xx]));
            const u32 hi = f2bf(lrelu(acc[2 * xx + 1]));
            dst[xx] = lo | (hi << 16);
        }
    }
    __syncthreads();   // h2s dead; c2s may be written

    // conv2: [16,14,14] -> [8,28,28], k=4, s=2 — two x-half passes
    if (tid < 224) {
        const int co = tid / 28, y = tid % 28;
        const float bv = cb2g[co];
        conv2_half<0>(c1s, c2s, cw2g, bv, co, y);
        conv2_half<1>(c1s, c2s, cw2g, bv, co, y);
    }
    __syncthreads();

    // conv3: [8,28,28] -> [1,28,28], k=3, s=1, tanh
    if (tid < 196) {
        const int y = tid / 7, qq = tid % 7;
        const int xb = qq * 4;
        float acc[4] = {cb3v, cb3v, cb3v, cb3v};
        for (int ci = 0; ci < 8; ++ci) {
            float wv[9];
            #pragma unroll
            for (int j = 0; j < 9; ++j) wv[j] = w3s[ci * 9 + j];
            #pragma unroll
            for (int a = 0; a < 3; ++a) {
                const int iy = y + 1 - a;
                if ((unsigned)iy < 28u) {
                    float rr[6];
                    #pragma unroll
                    for (int j = 0; j < 6; ++j) {
                        const int ix = xb - 1 + j;
                        rr[j] = ((unsigned)ix < 28u) ? bf1(c2s[ci][iy][ix]) : 0.f;
                    }
                    #pragma unroll
                    for (int xx = 0; xx < 4; ++xx)
                        #pragma unroll
                        for (int c = 0; c < 3; ++c)
                            acc[xx] += rr[xx + 2 - c] * wv[a * 3 + c];
                }
            }
        }
        float* op = out + (size_t)b * 784 + y * 28 + xb;
        #pragma unroll
        for (int xx = 0; xx < 4; ++xx) op[xx] = fast_tanh(acc[xx]);
    }
}

extern "C" void kernel_launch(void* const* d_in, const int* in_sizes, int n_in,
                              void* d_out, int out_size, void* d_ws, size_t ws_size,
                              hipStream_t stream) {
    const float* z   = (const float*)d_in[0];
    const int*   gi  = (const int*)d_in[1];
    const float* W1  = (const float*)d_in[2];
    const float* b1  = (const float*)d_in[3];
    const float* W2  = (const float*)d_in[4];
    const float* b2  = (const float*)d_in[5];
    const float* cw1 = (const float*)d_in[6];
    const float* cb1 = (const float*)d_in[7];
    const float* cw2 = (const float*)d_in[8];
    const float* cb2 = (const float*)d_in[9];
    const float* cw3 = (const float*)d_in[10];
    const float* cb3 = (const float*)d_in[11];
    int*      wsi = (int*)d_ws;
    float*    h1g = (float*)((char*)d_ws + WS_H1_OFF);
    u16*      h2g = (u16*)((char*)d_ws + WS_H2_OFF);
    _Float16* w2t = (_Float16*)((char*)d_ws + WS_W2T_OFF);

    prep_kernel<<<NB_W2T + NB_SLICE, 256, 0, stream>>>(z, gi, W1, b1, W2, wsi, h1g, w2t);
    fc2_kernel<<<NGEN * 64 * NCT, 256, 0, stream>>>(w2t, b2, wsi, h1g, h2g);
    conv_kernel<<<BATCH, 256, 0, stream>>>(gi, cw1, cb1, cw2, cb2, cw3, cb3,
                                           h2g, (float*)d_out);
}

// Round 16
// 206.230 us; speedup vs baseline: 1.0413x; 1.0413x over previous
//
#include <hip/hip_runtime.h>
#include <cstdint>
#include <cstddef>

#define BATCH 2048
#define NZ 128
#define NGEN 8
#define GRPS 32                 // samples per fc2 group
#define NCT 13                  // fc2 col tiles of 128 (12 full + tail 32)
#define H2_ELEMS 1792           // 32*7*8 (x padded 7->8) per sample, bf16
// ws layout: wsi ints [0 .. 16+8*2048) = 65.6 KB
#define WS_H1_OFF 81920                                  // h1[sample][col] fp32, 2 MB
#define WS_H2_OFF (WS_H1_OFF + BATCH * 256 * 4)          // 2179072
#define WS_W2T_OFF (WS_H2_OFF + BATCH * H2_ELEMS * 2)    // 9519104
#define W2T_GSTRIDE (1568 * 256)                         // fp16 elems per gen
#define NB_W2T (NGEN * 49)                               // 392
#define NB_SLICE (NGEN * 256)                            // 2048 bin+fc1 slice blocks

typedef unsigned int u32;
typedef unsigned short u16;
typedef _Float16 f16x8 __attribute__((ext_vector_type(8)));
typedef _Float16 f16x4 __attribute__((ext_vector_type(4)));
typedef float f32x4 __attribute__((ext_vector_type(4)));

__device__ __forceinline__ float lrelu(float x) { return fmaxf(x, 0.2f * x); }
__device__ __forceinline__ float bflo(u32 u) { union { u32 i; float f; } v; v.i = u << 16; return v.f; }
__device__ __forceinline__ float bfhi(u32 u) { union { u32 i; float f; } v; v.i = u & 0xffff0000u; return v.f; }
__device__ __forceinline__ float bf1(u16 u) { union { u32 i; float f; } v; v.i = ((u32)u) << 16; return v.f; }
__device__ __forceinline__ u16 f2bf(float f) {
    union { float f; u32 i; } v; v.f = f;
    u32 r = v.i + 0x7fffu + ((v.i >> 16) & 1u);   // round-to-nearest-even
    return (u16)(r >> 16);
}
__device__ __forceinline__ float fast_tanh(float x) {
    x = fminf(fmaxf(x, -9.f), 9.f);
    const float e = __expf(2.f * x);
    return (e - 1.f) / (e + 1.f);
}

// ---------------------------------------------------------------------------
// Kernel 1: prep (R14-proven) — three roles, no upstream dependency:
//   [0,392):   W2 transpose fp32[k][n] -> fp16[n][k]
//   [392,2440): bin+fc1 slice (g = idx>>8, s = idx&255): redundant in-block
//     bin via shuffle prefix; slice 0 publishes g's list; all slices do FC1.
// ---------------------------------------------------------------------------
__global__ __launch_bounds__(256) void prep_kernel(
    const float* __restrict__ z, const int* __restrict__ g_idx,
    const float* __restrict__ W1, const float* __restrict__ b1,
    const float* __restrict__ W2, int* __restrict__ wsi,
    float* __restrict__ h1g, _Float16* __restrict__ W2T)
{
    __shared__ _Float16 t[32][264];   // w2t role, 16.5 KB
    __shared__ u16 slist[BATCH];      // bin role, 4 KB
    __shared__ int wtot[4];
    __shared__ float zst[NZ][12];     // fc1 role, 6 KB
    __shared__ int sbv[8];

    const int tid = threadIdx.x;
    const int bx = blockIdx.x;

    if (bx < NB_W2T) {
        const int g = bx / 49;
        const int n0 = (bx % 49) * 32;
        const float* src = W2 + (size_t)g * 256 * 1568;
        const int nl = tid & 31, kh = tid >> 5;
        #pragma unroll 8
        for (int p = 0; p < 32; ++p) {
            const int k = p * 8 + kh;
            t[nl][k] = (_Float16)src[(size_t)k * 1568 + n0 + nl];
        }
        __syncthreads();
        _Float16* dst = W2T + (size_t)g * W2T_GSTRIDE + (size_t)n0 * 256;
        const int n = tid >> 3, k0 = (tid & 7) * 32;
        #pragma unroll
        for (int j = 0; j < 4; ++j)
            *(uint4*)(dst + (size_t)n * 256 + k0 + 8 * j) = *(const uint4*)&t[n][k0 + 8 * j];
        return;
    }

    const int idx = bx - NB_W2T;
    const int g = idx >> 8;
    const int s = idx & 255;

    int match[8];
    int lc = 0;
    {
        const int4 ga = ((const int4*)g_idx)[2 * tid];
        const int4 gb = ((const int4*)g_idx)[2 * tid + 1];
        const int gv[8] = {ga.x, ga.y, ga.z, ga.w, gb.x, gb.y, gb.z, gb.w};
        #pragma unroll
        for (int j = 0; j < 8; ++j)
            if (gv[j] == g) match[lc++] = 8 * tid + j;
    }
    const int lane = tid & 63, wv = tid >> 6;
    int px = lc;
    #pragma unroll
    for (int d = 1; d < 64; d <<= 1) {
        const int y = __shfl_up(px, d);
        if (lane >= d) px += y;
    }
    if (lane == 63) wtot[wv] = px;
    __syncthreads();
    int woff = 0, cnt = 0;
    #pragma unroll
    for (int w = 0; w < 4; ++w) {
        if (w < wv) woff += wtot[w];
        cnt += wtot[w];
    }
    const int myoff = woff + px - lc;
    for (int j = 0; j < lc; ++j) slist[myoff + j] = (u16)match[j];
    __syncthreads();

    if (s == 0) {
        if (tid == 0) wsi[8 + g] = cnt;
        const int padded = ((cnt + GRPS - 1) / GRPS) * GRPS;
        for (int i = tid; i < padded; i += 256)
            wsi[16 + g * 2048 + i] = (i < cnt) ? (int)slist[i] : -1;
    }
    if (s * 8 >= cnt) return;

    if (tid < 8) sbv[tid] = (s * 8 + tid < cnt) ? (int)slist[s * 8 + tid] : -1;
    __syncthreads();
    {
        const int ss = tid >> 5, f = tid & 31;
        float4 v = make_float4(0.f, 0.f, 0.f, 0.f);
        if (sbv[ss] >= 0) v = *(const float4*)(z + (size_t)sbv[ss] * NZ + 4 * f);
        zst[4 * f + 0][ss] = v.x; zst[4 * f + 1][ss] = v.y;
        zst[4 * f + 2][ss] = v.z; zst[4 * f + 3][ss] = v.w;
    }
    __syncthreads();

    const float* W1g = W1 + g * (NZ * 256);
    const int c = tid;
    float acc[8];
    #pragma unroll
    for (int ss = 0; ss < 8; ++ss) acc[ss] = 0.f;
    const float* wp = W1g + c;
    #pragma unroll 4
    for (int k = 0; k < NZ; ++k) {
        const float w = wp[k * 256];
        float av[8];
        *(float4*)&av[0] = *(const float4*)&zst[k][0];
        *(float4*)&av[4] = *(const float4*)&zst[k][4];
        #pragma unroll
        for (int ss = 0; ss < 8; ++ss) acc[ss] += av[ss] * w;
    }
    const float bv = b1[g * 256 + c];
    #pragma unroll
    for (int ss = 0; ss < 8; ++ss) {
        const int bb = sbv[ss];
        if (bb >= 0) h1g[(size_t)bb * 256 + c] = lrelu(acc[ss] + bv);
    }
}

// ---------------------------------------------------------------------------
// Kernel 2: FC2 via fp16 MFMA 16x16x32 (R13/R14-proven).
// ---------------------------------------------------------------------------
__global__ __launch_bounds__(256) void fc2_kernel(
    const _Float16* __restrict__ W2T, const float* __restrict__ b2,
    const int* __restrict__ wsi, const float* __restrict__ h1g,
    u16* __restrict__ h2g)
{
    __shared__ _Float16 afrag[2 * 2 * 8 * 64 * 8];   // 32 KB
    __shared__ int sb[GRPS];

    const int tid = threadIdx.x;
    const int grp = blockIdx.x / NCT;
    const int tile = blockIdx.x % NCT;
    const int gg = grp >> 6;
    const int j = grp & 63;
    const int cnt = wsi[8 + gg];
    if (j * GRPS >= cnt) return;

    if (tid < GRPS) sb[tid] = wsi[16 + gg * 2048 + j * GRPS + tid];
    __syncthreads();
    const _Float16* W2Tg = W2T + (size_t)gg * W2T_GSTRIDE;
    const float* b2g = b2 + gg * 1568;

    {
        const float4* h1p4 = (const float4*)h1g;
        #pragma unroll
        for (int i = 0; i < 8; ++i) {
            const int u = tid + 256 * i;
            const int j4 = u & 1;
            const int lane = (u >> 1) & 63;
            const int kq = (u >> 7) & 7;
            const int mt = (u >> 10) & 1;
            const int s = mt * 16 + (lane & 15);
            const int bb = sb[s];
            float4 v = make_float4(0.f, 0.f, 0.f, 0.f);
            if (bb >= 0) v = h1p4[(size_t)bb * 64 + kq * 8 + ((lane >> 4) << 1) + j4];
            const float vv[4] = {v.x, v.y, v.z, v.w};
            f16x4 hi, lo;
            #pragma unroll
            for (int e = 0; e < 4; ++e) {
                hi[e] = (_Float16)vv[e];
                lo[e] = (_Float16)(vv[e] - (float)hi[e]);
            }
            *(f16x4*)&afrag[(((mt * 2 + 0) * 8 + kq) * 64 + lane) * 8 + 4 * j4] = hi;
            *(f16x4*)&afrag[(((mt * 2 + 1) * 8 + kq) * 64 + lane) * 8 + 4 * j4] = lo;
        }
    }
    __syncthreads();

    const int wave = tid >> 6;
    const int lane = tid & 63;
    const int q = lane >> 4;
    const int nl = lane & 15;
    const int nb0 = tile * 128 + 2 * wave * 16;
    if (nb0 >= 1568) return;

    #pragma unroll
    for (int nt = 0; nt < 2; ++nt) {
        const int nb = nb0 + nt * 16;
        if (nb >= 1568) break;
        const int n = nb + nl;
        const _Float16* bp = W2Tg + (size_t)n * 256 + q * 8;
        f32x4 accA = {0.f, 0.f, 0.f, 0.f}, accB = accA;
        #pragma unroll
        for (int kq = 0; kq < 8; ++kq) {
            const f16x8 b = *(const f16x8*)(bp + kq * 32);
            const f16x8 a0h = *(const f16x8*)&afrag[((0 * 8 + kq) * 64 + lane) * 8];
            const f16x8 a0l = *(const f16x8*)&afrag[((1 * 8 + kq) * 64 + lane) * 8];
            const f16x8 a1h = *(const f16x8*)&afrag[((2 * 8 + kq) * 64 + lane) * 8];
            const f16x8 a1l = *(const f16x8*)&afrag[((3 * 8 + kq) * 64 + lane) * 8];
            accA = __builtin_amdgcn_mfma_f32_16x16x32_f16(a0h, b, accA, 0, 0, 0);
            accA = __builtin_amdgcn_mfma_f32_16x16x32_f16(a0l, b, accA, 0, 0, 0);
            accB = __builtin_amdgcn_mfma_f32_16x16x32_f16(a1h, b, accB, 0, 0, 0);
            accB = __builtin_amdgcn_mfma_f32_16x16x32_f16(a1l, b, accB, 0, 0, 0);
        }
        const float bias = b2g[n];
        const int ci = n / 49, rm = n % 49;
        const int off = ci * 56 + (rm / 7) * 8 + (rm % 7);
        #pragma unroll
        for (int mt = 0; mt < 2; ++mt) {
            const f32x4 a = (mt == 0) ? accA : accB;
            #pragma unroll
            for (int reg = 0; reg < 4; ++reg) {
                const int ss = mt * 16 + q * 4 + reg;
                const int bb = sb[ss];
                if (bb >= 0)
                    h2g[(size_t)bb * H2_ELEMS + off] = f2bf(lrelu(a[reg] + bias));
            }
        }
    }
}

// ---------------------------------------------------------------------------
// conv2 co-PAIR half-pass: one rr load stream + one address chain serve TWO
// co rows (halves conv2's LDS instrs, weight loads, and addressing VALU).
// Output x in [14*H, 14*H+14) for (co0, co0+1, y). c1s fp32 (R10 layout).
// Peak live regs ~55 (acc[2][14]+rr[12]+2xw4): fits plain launch_bounds.
// ---------------------------------------------------------------------------
template <int H>
__device__ __forceinline__ void conv2_pair(
    const float (*c1s)[14][20], u16 (*c2s)[28][30],
    const float* cw2g, const float bv0, const float bv1,
    const int co0, const int y)
{
    float acc[2][14];
    #pragma unroll
    for (int xx = 0; xx < 14; ++xx) { acc[0][xx] = bv0; acc[1][xx] = bv1; }
    const int a0 = (y + 1) & 1;
    for (int aa = 0; aa < 2; ++aa) {
        const int a = a0 + 2 * aa;
        const int iy = (y + 1 - a) >> 1;
        if ((unsigned)iy < 14u) {
            for (int ci = 0; ci < 16; ++ci) {
                // rr[j] = c1s[ci][iy][4*H + j]
                float rr[12];
                if (H == 0) {
                    *(float4*)&rr[0] = *(const float4*)&c1s[ci][iy][0];
                    *(float4*)&rr[4] = *(const float4*)&c1s[ci][iy][4];
                } else {
                    *(float4*)&rr[0] = *(const float4*)&c1s[ci][iy][4];
                    *(float4*)&rr[4] = *(const float4*)&c1s[ci][iy][8];
                    *(float4*)&rr[8] = *(const float4*)&c1s[ci][iy][12];
                }
                const float4 w40 = *(const float4*)(cw2g + ci * 128 + co0 * 16 + a * 4);
                const float4 w41 = *(const float4*)(cw2g + ci * 128 + (co0 + 1) * 16 + a * 4);
                const float wv0[4] = {w40.x, w40.y, w40.z, w40.w};
                const float wv1[4] = {w41.x, w41.y, w41.z, w41.w};
                #pragma unroll
                for (int xx = 0; xx < 14; ++xx) {
                    const int x = 14 * H + xx;
                    const int c0v = (x + 1) & 1;
                    const int ix0 = (x + 1 - c0v) >> 1;
                    const int li = ix0 - 4 * H;            // compile-time
                    if (ix0 < 14) {
                        acc[0][xx] += rr[li] * wv0[c0v];
                        acc[1][xx] += rr[li] * wv1[c0v];
                    }
                    if (ix0 >= 1) {
                        acc[0][xx] += rr[li - 1] * wv0[c0v + 2];
                        acc[1][xx] += rr[li - 1] * wv1[c0v + 2];
                    }
                }
            }
        }
    }
    #pragma unroll
    for (int cc = 0; cc < 2; ++cc) {
        u32* dst = (u32*)&c2s[co0 + cc][y][0];
        #pragma unroll
        for (int xx = 0; xx < 7; ++xx) {
            const u32 lo = f2bf(lrelu(acc[cc][2 * xx]));
            const u32 hi = f2bf(lrelu(acc[cc][2 * xx + 1]));
            dst[7 * H + xx] = lo | (hi << 16);
        }
    }
}

// ---------------------------------------------------------------------------
// Kernel 3: all three transposed convs, ONE sample per block.
// conv1/conv3: R10-proven form. conv2: co-paired + x-halves (224 threads).
// Plain __launch_bounds__(256): allocator free to expand (R3 lesson) — no
// min-waves clamp that pinned VGPR=48 and spilled in R11. LDS 31.4 KB.
// ---------------------------------------------------------------------------
__global__ __launch_bounds__(256) void conv_kernel(
    const int* __restrict__ g_idx,
    const float* __restrict__ cw1, const float* __restrict__ cb1,
    const float* __restrict__ cw2, const float* __restrict__ cb2,
    const float* __restrict__ cw3, const float* __restrict__ cb3,
    const u16* __restrict__ h2g, float* __restrict__ out)
{
    __shared__ __align__(16) char smem[13440 + 17920];
    float (*h2s)[7][8]   = (float (*)[7][8])smem;            // [32][7][8]
    u16  (*c2s)[28][30]  = (u16 (*)[28][30])smem;            // [8][28][30] (alias)
    float (*c1s)[14][20] = (float (*)[14][20])(smem + 13440);
    __shared__ float w3s[72];

    const int tid = threadIdx.x;
    const int b = blockIdx.x;
    const int g = g_idx[b];
    const float* cw1g = cw1 + g * 8192;
    const float* cb1g = cb1 + g * 16;
    const float* cw2g = cw2 + g * 2048;
    const float* cb2g = cb2 + g * 8;
    const float* cw3g = cw3 + g * 72;
    const float  cb3v = cb3[g];

    if (tid < 224) {
        const uint4 qv = ((const uint4*)(h2g + (size_t)b * H2_ELEMS))[tid];
        float* hp = (float*)h2s + 8 * tid;
        ((float4*)hp)[0] = make_float4(bflo(qv.x), bfhi(qv.x), bflo(qv.y), bfhi(qv.y));
        ((float4*)hp)[1] = make_float4(bflo(qv.z), bfhi(qv.z), bflo(qv.w), bfhi(qv.w));
    }
    if (tid < 72) w3s[tid] = cw3g[tid];
    __syncthreads();

    // conv1: [32,7,7] -> [16,14,14], k=4, s=2 (R10-proven form)
    if (tid < 224) {
        const int co = tid / 14, y = tid % 14;
        float acc[14];
        const float bv = cb1g[co];
        #pragma unroll
        for (int x = 0; x < 14; ++x) acc[x] = bv;
        const int a0 = (y + 1) & 1;
        for (int aa = 0; aa < 2; ++aa) {
            const int a = a0 + 2 * aa;
            const int iy = (y + 1 - a) >> 1;
            if ((unsigned)iy < 7u) {
                #pragma unroll 2
                for (int ci = 0; ci < 32; ++ci) {
                    float rr[8];
                    *(float4*)&rr[0] = *(const float4*)&h2s[ci][iy][0];
                    *(float4*)&rr[4] = *(const float4*)&h2s[ci][iy][4];
                    const float4 w4 = *(const float4*)(cw1g + ci * 256 + co * 16 + a * 4);
                    const float wv[4] = {w4.x, w4.y, w4.z, w4.w};
                    #pragma unroll
                    for (int x = 0; x < 14; ++x) {
                        const int c0v = (x + 1) & 1;
                        const int ix0 = (x + 1 - c0v) >> 1;
                        if (ix0 < 7)  acc[x] += rr[ix0] * wv[c0v];
                        if (ix0 >= 1) acc[x] += rr[ix0 - 1] * wv[c0v + 2];
                    }
                }
            }
        }
        #pragma unroll
        for (int x = 0; x < 14; ++x) acc[x] = lrelu(acc[x]);
        *(float4*)&c1s[co][y][0]  = *(float4*)&acc[0];
        *(float4*)&c1s[co][y][4]  = *(float4*)&acc[4];
        *(float4*)&c1s[co][y][8]  = *(float4*)&acc[8];
        *(float2*)&c1s[co][y][12] = *(float2*)&acc[12];
    }
    __syncthreads();   // h2s dead; c2s may be written

    // conv2: [16,14,14] -> [8,28,28] — co-paired + x-halves, 224 threads
    if (tid < 224) {
        const int y = tid % 28;
        const int cg = tid / 28;          // 0..7
        const int co0 = 2 * (cg & 3);
        const float bv0 = cb2g[co0], bv1 = cb2g[co0 + 1];
        if (cg < 4) conv2_pair<0>(c1s, c2s, cw2g, bv0, bv1, co0, y);
        else        conv2_pair<1>(c1s, c2s, cw2g, bv0, bv1, co0, y);
    }
    __syncthreads();

    // conv3: [8,28,28] -> [1,28,28], k=3, s=1, tanh (R10-proven form)
    if (tid < 196) {
        const int y = tid / 7, qq = tid % 7;
        const int xb = qq * 4;
        float acc[4] = {cb3v, cb3v, cb3v, cb3v};
        for (int ci = 0; ci < 8; ++ci) {
            float wv[9];
            #pragma unroll
            for (int j = 0; j < 9; ++j) wv[j] = w3s[ci * 9 + j];
            #pragma unroll
            for (int a = 0; a < 3; ++a) {
                const int iy = y + 1 - a;
                if ((unsigned)iy < 28u) {
                    float rr[6];
                    #pragma unroll
                    for (int j = 0; j < 6; ++j) {
                        const int ix = xb - 1 + j;
                        rr[j] = ((unsigned)ix < 28u) ? bf1(c2s[ci][iy][ix]) : 0.f;
                    }
                    #pragma unroll
                    for (int xx = 0; xx < 4; ++xx)
                        #pragma unroll
                        for (int c = 0; c < 3; ++c)
                            acc[xx] += rr[xx + 2 - c] * wv[a * 3 + c];
                }
            }
        }
        float* op = out + (size_t)b * 784 + y * 28 + xb;
        #pragma unroll
        for (int xx = 0; xx < 4; ++xx) op[xx] = fast_tanh(acc[xx]);
    }
}

extern "C" void kernel_launch(void* const* d_in, const int* in_sizes, int n_in,
                              void* d_out, int out_size, void* d_ws, size_t ws_size,
                              hipStream_t stream) {
    const float* z   = (const float*)d_in[0];
    const int*   gi  = (const int*)d_in[1];
    const float* W1  = (const float*)d_in[2];
    const float* b1  = (const float*)d_in[3];
    const float* W2  = (const float*)d_in[4];
    const float* b2  = (const float*)d_in[5];
    const float* cw1 = (const float*)d_in[6];
    const float* cb1 = (const float*)d_in[7];
    const float* cw2 = (const float*)d_in[8];
    const float* cb2 = (const float*)d_in[9];
    const float* cw3 = (const float*)d_in[10];
    const float* cb3 = (const float*)d_in[11];
    int*      wsi = (int*)d_ws;
    float*    h1g = (float*)((char*)d_ws + WS_H1_OFF);
    u16*      h2g = (u16*)((char*)d_ws + WS_H2_OFF);
    _Float16* w2t = (_Float16*)((char*)d_ws + WS_W2T_OFF);

    prep_kernel<<<NB_W2T + NB_SLICE, 256, 0, stream>>>(z, gi, W1, b1, W2, wsi, h1g, w2t);
    fc2_kernel<<<NGEN * 64 * NCT, 256, 0, stream>>>(w2t, b2, wsi, h1g, h2g);
    conv_kernel<<<BATCH, 256, 0, stream>>>(gi, cw1, cb1, cw2, cb2, cw3, cb3,
                                           h2g, (float*)d_out);
}

// Round 17
// 198.678 us; speedup vs baseline: 1.0809x; 1.0380x over previous
//
#include <hip/hip_runtime.h>
#include <cstdint>
#include <cstddef>

#define BATCH 2048
#define NZ 128
#define NGEN 8
#define GRPS 32                 // samples per group (same generator)
#define MAXG 72                 // max padded groups
#define NCT 13                  // fc2 col tiles of 128 (12 full + tail 32)
#define H2_ELEMS 1792           // 32*7*8 (x padded 7->8) per sample, bf16
#define WS_H1_OFF 16384                                  // h1: 72*8192 fp32
#define WS_H2_OFF (16384 + MAXG * 8192 * 4)              // 2375680
#define WS_W2T_OFF (WS_H2_OFF + BATCH * H2_ELEMS * 2)    // 9715712
#define W2T_GSTRIDE (1568 * 256)                         // fp16 elems per gen
#define NB_W2T (NGEN * 49)                               // 392

typedef unsigned int u32;
typedef unsigned short u16;
typedef _Float16 f16x8 __attribute__((ext_vector_type(8)));
typedef _Float16 f16x4 __attribute__((ext_vector_type(4)));
typedef float f32x4 __attribute__((ext_vector_type(4)));

__device__ __forceinline__ float lrelu(float x) { return fmaxf(x, 0.2f * x); }
__device__ __forceinline__ float bflo(u32 u) { union { u32 i; float f; } v; v.i = u << 16; return v.f; }
__device__ __forceinline__ float bfhi(u32 u) { union { u32 i; float f; } v; v.i = u & 0xffff0000u; return v.f; }
__device__ __forceinline__ float bf1(u16 u) { union { u32 i; float f; } v; v.i = ((u32)u) << 16; return v.f; }
__device__ __forceinline__ u16 f2bf(float f) {
    union { float f; u32 i; } v; v.f = f;
    u32 r = v.i + 0x7fffu + ((v.i >> 16) & 1u);   // round-to-nearest-even
    return (u16)(r >> 16);
}
__device__ __forceinline__ float fast_tanh(float x) {
    x = fminf(fmaxf(x, -9.f), 9.f);
    const float e = __expf(2.f * x);
    return (e - 1.f) / (e + 1.f);
}

// ---------------------------------------------------------------------------
// Kernel 1: bin samples by generator (R10-proven 1-block form).
// wsi[0] = padded total; wsi[16..] = ids grouped, groups padded to 32 w/ -1.
// ---------------------------------------------------------------------------
__global__ void bin_kernel(const int* __restrict__ g_idx, int* __restrict__ wsi) {
    __shared__ int cnt[NGEN];
    __shared__ int pbase[NGEN + 1];
    __shared__ u16 rank[BATCH];
    const int tid = threadIdx.x;
    if (tid < NGEN) cnt[tid] = 0;
    __syncthreads();
    for (int b = tid; b < BATCH; b += 256) {
        int g = g_idx[b];
        rank[b] = (u16)atomicAdd(&cnt[g], 1);
    }
    __syncthreads();
    if (tid == 0) {
        int acc = 0;
        for (int g = 0; g < NGEN; ++g) {
            pbase[g] = acc;
            acc += ((cnt[g] + GRPS - 1) / GRPS) * GRPS;
        }
        pbase[NGEN] = acc;
        wsi[0] = acc;
    }
    __syncthreads();
    const int total = pbase[NGEN];
    for (int i = tid; i < total; i += 256) wsi[16 + i] = -1;
    __syncthreads();
    for (int b = tid; b < BATCH; b += 256) {
        int g = g_idx[b];
        wsi[16 + pbase[g] + (int)rank[b]] = b;
    }
}

// ---------------------------------------------------------------------------
// Kernel 2: prep = W2 transpose (blocks 0..391) + grouped FC1 (392..679).
// h1g layout [grp][sample 32][col 256] fp32 (group-local).
// ---------------------------------------------------------------------------
__global__ __launch_bounds__(256) void prep_kernel(
    const float* __restrict__ z, const int* __restrict__ g_idx,
    const float* __restrict__ W1, const float* __restrict__ b1,
    const float* __restrict__ W2, const int* __restrict__ wsi,
    float* __restrict__ h1g, _Float16* __restrict__ W2T)
{
    __shared__ _Float16 t[32][264];   // w2t role, 16.5 KB
    __shared__ float zst[NZ][12];     // fc1 role, 6 KB
    __shared__ int sb[8];
    __shared__ int sG;

    const int tid = threadIdx.x;
    const int bx = blockIdx.x;

    if (bx < NB_W2T) {
        // ---- W2 transpose role: W2[g][k256][n1568] fp32 -> W2T[g][n][k] fp16
        const int g = bx / 49;
        const int n0 = (bx % 49) * 32;
        const float* src = W2 + (size_t)g * 256 * 1568;
        const int nl = tid & 31, kh = tid >> 5;
        #pragma unroll 8
        for (int p = 0; p < 32; ++p) {
            const int k = p * 8 + kh;
            t[nl][k] = (_Float16)src[(size_t)k * 1568 + n0 + nl];
        }
        __syncthreads();
        _Float16* dst = W2T + (size_t)g * W2T_GSTRIDE + (size_t)n0 * 256;
        const int n = tid >> 3, k0 = (tid & 7) * 32;
        #pragma unroll
        for (int j = 0; j < 4; ++j)
            *(uint4*)(dst + (size_t)n * 256 + k0 + 8 * j) = *(const uint4*)&t[n][k0 + 8 * j];
        return;
    }

    // ---- FC1 role (grouped): (group, 8-sample slice) ----
    const int bx2 = bx - NB_W2T;
    const int grp = bx2 >> 2;
    const int s0 = (bx2 & 3) * 8;
    if (grp * GRPS >= wsi[0]) return;

    if (tid == 0) sG = g_idx[wsi[16 + grp * GRPS]];
    if (tid < 8) sb[tid] = wsi[16 + grp * GRPS + s0 + tid];
    __syncthreads();
    const float* W1g = W1 + sG * (NZ * 256);
    const float* b1g = b1 + sG * 256;

    {   // stage z: 8 samples x 128 = 256 float4, one per thread
        const int s = tid >> 5, f = tid & 31;
        float4 v = make_float4(0.f, 0.f, 0.f, 0.f);
        if (sb[s] >= 0) v = *(const float4*)(z + (size_t)sb[s] * NZ + 4 * f);
        zst[4 * f + 0][s] = v.x; zst[4 * f + 1][s] = v.y;
        zst[4 * f + 2][s] = v.z; zst[4 * f + 3][s] = v.w;
    }
    __syncthreads();

    const int c = tid;
    float acc[8];
    #pragma unroll
    for (int s = 0; s < 8; ++s) acc[s] = 0.f;
    const float* wp = W1g + c;
    #pragma unroll 4
    for (int k = 0; k < NZ; ++k) {
        const float w = wp[k * 256];
        float av[8];
        *(float4*)&av[0] = *(const float4*)&zst[k][0];
        *(float4*)&av[4] = *(const float4*)&zst[k][4];
        #pragma unroll
        for (int s = 0; s < 8; ++s) acc[s] += av[s] * w;
    }
    const float bv = b1g[c];
    float* hp = h1g + (size_t)grp * 8192 + (size_t)s0 * 256 + c;
    #pragma unroll
    for (int s = 0; s < 8; ++s) hp[s * 256] = lrelu(acc[s] + bv);
}

// ---------------------------------------------------------------------------
// Kernel 3: FC2 via fp16 MFMA 16x16x32 — conflict-free staging + split-pass.
// Staging map: u = tid + 256*i -> j4=u&1, lane=(u>>1)&63, kq=(u>>7)&7,
// mt=(u>>10)&1; element = h1[s = mt*16+(lane&15)][k = kq*32+(lane>>4)*8+4*j4].
// LDS store addr = base + 8*tid B -> conflict-free; 64 B-clustered reads.
// K-loop one n-tile at a time (peak live regs ~50: spill-proof).
// C/D layout: col(n)=lane&15, row(m)=(lane>>4)*4+reg [m89].
// ---------------------------------------------------------------------------
__global__ __launch_bounds__(256) void fc2_kernel(
    const int* __restrict__ g_idx,
    const _Float16* __restrict__ W2T, const float* __restrict__ b2,
    const int* __restrict__ wsi, const float* __restrict__ h1g,
    u16* __restrict__ h2g)
{
    __shared__ _Float16 afrag[2 * 2 * 8 * 64 * 8];   // [mt*2+h][kq][lane][8], 32 KB
    __shared__ int sb[GRPS];
    __shared__ int sG;

    const int tid = threadIdx.x;
    const int grp = blockIdx.x / NCT;
    const int tile = blockIdx.x % NCT;
    if (grp * GRPS >= wsi[0]) return;

    if (tid == 0) sG = g_idx[wsi[16 + grp * GRPS]];
    if (tid < GRPS) sb[tid] = wsi[16 + grp * GRPS + tid];
    __syncthreads();
    const _Float16* W2Tg = W2T + (size_t)sG * W2T_GSTRIDE;
    const float* b2g = b2 + sG * 1568;

    // ---- stage A fragments (hi/lo split), conflict-free stores ----
    {
        const float4* h1p4 = (const float4*)(h1g + (size_t)grp * 8192);
        #pragma unroll
        for (int i = 0; i < 8; ++i) {
            const int u = tid + 256 * i;
            const int j4 = u & 1;                  // j base = 4*j4
            const int lane = (u >> 1) & 63;
            const int kq = (u >> 7) & 7;
            const int mt = (u >> 10) & 1;
            const int s = mt * 16 + (lane & 15);
            const float4 v = h1p4[s * 64 + kq * 8 + ((lane >> 4) << 1) + j4];
            const float vv[4] = {v.x, v.y, v.z, v.w};
            f16x4 hi, lo;
            #pragma unroll
            for (int e = 0; e < 4; ++e) {
                hi[e] = (_Float16)vv[e];
                lo[e] = (_Float16)(vv[e] - (float)hi[e]);
            }
            const int bh = (((mt * 2 + 0) * 8 + kq) * 64 + lane) * 8 + 4 * j4;
            const int bl = (((mt * 2 + 1) * 8 + kq) * 64 + lane) * 8 + 4 * j4;
            *(f16x4*)&afrag[bh] = hi;   // addr = base + 8*tid bytes: conflict-free
            *(f16x4*)&afrag[bl] = lo;
        }
    }
    __syncthreads();

    const int wave = tid >> 6;
    const int lane = tid & 63;
    const int q = lane >> 4;
    const int nl = lane & 15;
    const int nb0 = tile * 128 + 2 * wave * 16;
    if (nb0 >= 1568) return;

    #pragma unroll
    for (int nt = 0; nt < 2; ++nt) {
        const int nb = nb0 + nt * 16;
        if (nb >= 1568) break;
        const int n = nb + nl;
        const _Float16* bp = W2Tg + (size_t)n * 256 + q * 8;
        f32x4 accA = {0.f, 0.f, 0.f, 0.f}, accB = accA;
        #pragma unroll
        for (int kq = 0; kq < 8; ++kq) {
            const f16x8 b = *(const f16x8*)(bp + kq * 32);
            const f16x8 a0h = *(const f16x8*)&afrag[((0 * 8 + kq) * 64 + lane) * 8];
            const f16x8 a0l = *(const f16x8*)&afrag[((1 * 8 + kq) * 64 + lane) * 8];
            const f16x8 a1h = *(const f16x8*)&afrag[((2 * 8 + kq) * 64 + lane) * 8];
            const f16x8 a1l = *(const f16x8*)&afrag[((3 * 8 + kq) * 64 + lane) * 8];
            accA = __builtin_amdgcn_mfma_f32_16x16x32_f16(a0h, b, accA, 0, 0, 0);
            accA = __builtin_amdgcn_mfma_f32_16x16x32_f16(a0l, b, accA, 0, 0, 0);
            accB = __builtin_amdgcn_mfma_f32_16x16x32_f16(a1h, b, accB, 0, 0, 0);
            accB = __builtin_amdgcn_mfma_f32_16x16x32_f16(a1l, b, accB, 0, 0, 0);
        }
        // epilogue for this n-tile
        const float bias = b2g[n];
        const int ci = n / 49, rm = n % 49;
        const int off = ci * 56 + (rm / 7) * 8 + (rm % 7);
        #pragma unroll
        for (int mt = 0; mt < 2; ++mt) {
            const f32x4 a = (mt == 0) ? accA : accB;
            #pragma unroll
            for (int reg = 0; reg < 4; ++reg) {
                const int s = mt * 16 + q * 4 + reg;
                const int bb = sb[s];
                if (bb >= 0)
                    h2g[(size_t)bb * H2_ELEMS + off] = f2bf(lrelu(a[reg] + bias));
            }
        }
    }
}

// ---------------------------------------------------------------------------
// conv2 half-pass (R10-proven): output x in [14*H, 14*H+14).
// ---------------------------------------------------------------------------
template <int H>
__device__ __forceinline__ void conv2_half(
    const float (*c1s)[14][20], u16 (*c2s)[28][30],
    const float* cw2g, const float bv, const int co, const int y)
{
    float acc[14];
    #pragma unroll
    for (int xx = 0; xx < 14; ++xx) acc[xx] = bv;
    const int a0 = (y + 1) & 1;
    for (int aa = 0; aa < 2; ++aa) {
        const int a = a0 + 2 * aa;
        const int iy = (y + 1 - a) >> 1;
        if ((unsigned)iy < 14u) {
            #pragma unroll 2
            for (int ci = 0; ci < 16; ++ci) {
                float rr[12];
                if (H == 0) {
                    *(float4*)&rr[0] = *(const float4*)&c1s[ci][iy][0];
                    *(float4*)&rr[4] = *(const float4*)&c1s[ci][iy][4];
                } else {
                    *(float4*)&rr[0] = *(const float4*)&c1s[ci][iy][4];
                    *(float4*)&rr[4] = *(const float4*)&c1s[ci][iy][8];
                    *(float4*)&rr[8] = *(const float4*)&c1s[ci][iy][12];
                }
                const float4 w4 = *(const float4*)(cw2g + ci * 128 + co * 16 + a * 4);
                const float wv[4] = {w4.x, w4.y, w4.z, w4.w};
                #pragma unroll
                for (int xx = 0; xx < 14; ++xx) {
                    const int x = 14 * H + xx;
                    const int c0v = (x + 1) & 1;
                    const int ix0 = (x + 1 - c0v) >> 1;
                    const int li = ix0 - 4 * H;
                    if (ix0 < 14) acc[xx] += rr[li] * wv[c0v];
                    if (ix0 >= 1) acc[xx] += rr[li - 1] * wv[c0v + 2];
                }
            }
        }
    }
    u32* dst = (u32*)&c2s[co][y][0];
    #pragma unroll
    for (int xx = 0; xx < 7; ++xx) {
        const u32 lo = f2bf(lrelu(acc[2 * xx]));
        const u32 hi = f2bf(lrelu(acc[2 * xx + 1]));
        dst[7 * H + xx] = lo | (hi << 16);
    }
}

// ---------------------------------------------------------------------------
// Kernel 4: all three transposed convs, ONE sample per block (R10-proven).
// LDS aliasing: c2s over dead h2s. ~31.4 KB, 5 blocks/CU. VGPR 48, no spill.
// Hardened local optimum: bf16-c1s (R15), co-pair+clamp (R11), co-pair
// free (R16) all regressed — conv is VALU-issue-bound at this occupancy.
// ---------------------------------------------------------------------------
__global__ __launch_bounds__(256, 5) void conv_kernel(
    const int* __restrict__ g_idx,
    const float* __restrict__ cw1, const float* __restrict__ cb1,
    const float* __restrict__ cw2, const float* __restrict__ cb2,
    const float* __restrict__ cw3, const float* __restrict__ cb3,
    const u16* __restrict__ h2g, float* __restrict__ out)
{
    __shared__ __align__(16) char smem[13440 + 17920];
    float (*h2s)[7][8]   = (float (*)[7][8])smem;            // [32][7][8]
    u16  (*c2s)[28][30]  = (u16 (*)[28][30])smem;            // [8][28][30]
    float (*c1s)[14][20] = (float (*)[14][20])(smem + 13440);
    __shared__ float w3s[72];

    const int tid = threadIdx.x;
    const int b = blockIdx.x;
    const int g = g_idx[b];
    const float* cw1g = cw1 + g * 8192;
    const float* cb1g = cb1 + g * 16;
    const float* cw2g = cw2 + g * 2048;
    const float* cb2g = cb2 + g * 8;
    const float* cw3g = cw3 + g * 72;
    const float  cb3v = cb3[g];

    if (tid < 224) {
        const uint4 qv = ((const uint4*)(h2g + (size_t)b * H2_ELEMS))[tid];
        float* hp = (float*)h2s + 8 * tid;
        ((float4*)hp)[0] = make_float4(bflo(qv.x), bfhi(qv.x), bflo(qv.y), bfhi(qv.y));
        ((float4*)hp)[1] = make_float4(bflo(qv.z), bfhi(qv.z), bflo(qv.w), bfhi(qv.w));
    }
    if (tid < 72) w3s[tid] = cw3g[tid];
    __syncthreads();

    // conv1: [32,7,7] -> [16,14,14], k=4, s=2
    if (tid < 224) {
        const int co = tid / 14, y = tid % 14;
        float acc[14];
        const float bv = cb1g[co];
        #pragma unroll
        for (int x = 0; x < 14; ++x) acc[x] = bv;
        const int a0 = (y + 1) & 1;
        for (int aa = 0; aa < 2; ++aa) {
            const int a = a0 + 2 * aa;
            const int iy = (y + 1 - a) >> 1;
            if ((unsigned)iy < 7u) {
                #pragma unroll 2
                for (int ci = 0; ci < 32; ++ci) {
                    float rr[8];
                    *(float4*)&rr[0] = *(const float4*)&h2s[ci][iy][0];
                    *(float4*)&rr[4] = *(const float4*)&h2s[ci][iy][4];
                    const float4 w4 = *(const float4*)(cw1g + ci * 256 + co * 16 + a * 4);
                    const float wv[4] = {w4.x, w4.y, w4.z, w4.w};
                    #pragma unroll
                    for (int x = 0; x < 14; ++x) {
                        const int c0v = (x + 1) & 1;
                        const int ix0 = (x + 1 - c0v) >> 1;
                        if (ix0 < 7)  acc[x] += rr[ix0] * wv[c0v];
                        if (ix0 >= 1) acc[x] += rr[ix0 - 1] * wv[c0v + 2];
                    }
                }
            }
        }
        #pragma unroll
        for (int x = 0; x < 14; ++x) acc[x] = lrelu(acc[x]);
        *(float4*)&c1s[co][y][0]  = *(float4*)&acc[0];
        *(float4*)&c1s[co][y][4]  = *(float4*)&acc[4];
        *(float4*)&c1s[co][y][8]  = *(float4*)&acc[8];
        *(float2*)&c1s[co][y][12] = *(float2*)&acc[12];
    }
    __syncthreads();   // h2s dead; c2s may be written

    if (tid < 224) {
        const int co = tid / 28, y = tid % 28;
        const float bv = cb2g[co];
        conv2_half<0>(c1s, c2s, cw2g, bv, co, y);
        conv2_half<1>(c1s, c2s, cw2g, bv, co, y);
    }
    __syncthreads();

    if (tid < 196) {
        const int y = tid / 7, qq = tid % 7;
        const int xb = qq * 4;
        float acc[4] = {cb3v, cb3v, cb3v, cb3v};
        for (int ci = 0; ci < 8; ++ci) {
            float wv[9];
            #pragma unroll
            for (int j = 0; j < 9; ++j) wv[j] = w3s[ci * 9 + j];
            #pragma unroll
            for (int a = 0; a < 3; ++a) {
                const int iy = y + 1 - a;
                if ((unsigned)iy < 28u) {
                    float rr[6];
                    #pragma unroll
                    for (int j = 0; j < 6; ++j) {
                        const int ix = xb - 1 + j;
                        rr[j] = ((unsigned)ix < 28u) ? bf1(c2s[ci][iy][ix]) : 0.f;
                    }
                    #pragma unroll
                    for (int xx = 0; xx < 4; ++xx)
                        #pragma unroll
                        for (int c = 0; c < 3; ++c)
                            acc[xx] += rr[xx + 2 - c] * wv[a * 3 + c];
                }
            }
        }
        float* op = out + (size_t)b * 784 + y * 28 + xb;
        #pragma unroll
        for (int xx = 0; xx < 4; ++xx) op[xx] = fast_tanh(acc[xx]);
    }
}

extern "C" void kernel_launch(void* const* d_in, const int* in_sizes, int n_in,
                              void* d_out, int out_size, void* d_ws, size_t ws_size,
                              hipStream_t stream) {
    const float* z   = (const float*)d_in[0];
    const int*   gi  = (const int*)d_in[1];
    const float* W1  = (const float*)d_in[2];
    const float* b1  = (const float*)d_in[3];
    const float* W2  = (const float*)d_in[4];
    const float* b2  = (const float*)d_in[5];
    const float* cw1 = (const float*)d_in[6];
    const float* cb1 = (const float*)d_in[7];
    const float* cw2 = (const float*)d_in[8];
    const float* cb2 = (const float*)d_in[9];
    const float* cw3 = (const float*)d_in[10];
    const float* cb3 = (const float*)d_in[11];
    int*      wsi = (int*)d_ws;
    float*    h1g = (float*)((char*)d_ws + WS_H1_OFF);
    u16*      h2g = (u16*)((char*)d_ws + WS_H2_OFF);
    _Float16* w2t = (_Float16*)((char*)d_ws + WS_W2T_OFF);

    bin_kernel<<<1, 256, 0, stream>>>(gi, wsi);
    prep_kernel<<<NB_W2T + MAXG * 4, 256, 0, stream>>>(z, gi, W1, b1, W2, wsi, h1g, w2t);
    fc2_kernel<<<MAXG * NCT, 256, 0, stream>>>(gi, w2t, b2, wsi, h1g, h2g);
    conv_kernel<<<BATCH, 256, 0, stream>>>(gi, cw1, cb1, cw2, cb2, cw3, cb3,
                                           h2g, (float*)d_out);
}